// Round 2
// baseline (354.695 us; speedup 1.0000x reference)
//
#include <hip/hip_runtime.h>
#include <hip/hip_fp16.h>
#include <hip/hip_cooperative_groups.h>

namespace cg = cooperative_groups;

#define N_TOT 65536
#define D_DIM 512
#define K_DIM 64
#define NC    32          // n-rows per chunk (one MFMA K=32 step)
#define HT_S  40          // LDS row stride in bf16 elems = 80 B (16B-aligned rows)
#define GSZ   (K_DIM * D_DIM)   // 32768 elements of partial G

typedef __bf16   bf16x8 __attribute__((ext_vector_type(8)));
typedef float    f32x4  __attribute__((ext_vector_type(4)));
typedef float    f32x2  __attribute__((ext_vector_type(2)));
typedef _Float16 half8  __attribute__((ext_vector_type(8)));

__device__ __forceinline__ unsigned int pack_bf16(float a, float b) {
    union { float f; unsigned int u; } x, y;
    x.f = a; y.f = b;
    unsigned int lo = (x.u + 0x7fffu + ((x.u >> 16) & 1u)) >> 16;   // RNE
    unsigned int hi = (y.u + 0x7fffu + ((y.u >> 16) & 1u)) >> 16;
    return lo | (hi << 16);
}

// Fused cooperative kernel:
//   Phase 1 (= old k1): partial G = F_c^T h_c via bf16 MFMA with T14 split staging
//     (issue chunk c+2 loads BEFORE MFMA(c); pack chunk c+1 from regs loaded one
//     iteration earlier -> vmcnt wait ~0, HBM queue never drains at barriers).
//   __threadfence + grid.sync  (device-scope flush -> gpart visible cross-XCD)
//   Phase 2 (= old k2): sum partials, accumulate -||G||^2 + trw into out.
extern "C" __global__ void __launch_bounds__(1024)
fused(const float* __restrict__ h, const float* __restrict__ F,
      unsigned short* __restrict__ gpart, float* __restrict__ out,
      int rowsPerBlock, int P) {
    __shared__ unsigned short ht[2][D_DIM * HT_S];   // 2 x 40960 B, ht[d][n]
    __shared__ unsigned short Ft[2][K_DIM * HT_S];   // 2 x  5120 B, Ft[k][n]
    __shared__ float red[16];
    __shared__ float sTrw;

    const int tid = threadIdx.x;
    const int b   = blockIdx.x;
    if (b == 0 && tid == 0) out[0] = 0.0f;    // flushed by threadfence before any atomicAdd

    const int row0    = b * rowsPerBlock;
    const int nChunks = rowsPerBlock / NC;    // >= 8

    // staging ids (h): lane owns d-quad; sg picks 4-row n-group
    const int sd = tid & 127;
    const int sg = tid >> 7;
    // staging ids (F): threads 0..255
    const int fk = (tid & 31) * 2;
    const int fg = tid >> 5;
    // mfma ids
    const int wave = tid >> 6;
    const int lane = tid & 63;
    const int m    = lane & 15;
    const int q    = lane >> 4;

    f32x4 acc[4][2];
    #pragma unroll
    for (int kt = 0; kt < 4; ++kt)
        #pragma unroll
        for (int dt = 0; dt < 2; ++dt)
            acc[kt][dt] = (f32x4){0.f, 0.f, 0.f, 0.f};

    float trw = 0.f;
    f32x4 hA[4], hB[4];      // two in-flight h-chunks (T14 split)
    f32x2 Fw[4];             // single-depth F split (F = 1/9 of traffic)

    auto issueH = [&](int c, f32x4 (&dst)[4]) {
        const float* hb = h + (size_t)(row0 + c * NC + sg * 4) * D_DIM + sd * 4;
        #pragma unroll
        for (int j = 0; j < 4; ++j)
            dst[j] = *(const f32x4*)(hb + (size_t)j * D_DIM);
    };
    auto issueF = [&](int c) {
        if (tid < 256) {
            const float* fb = F + (size_t)(row0 + c * NC + fg * 4) * K_DIM + fk;
            #pragma unroll
            for (int j = 0; j < 4; ++j)
                Fw[j] = *(const f32x2*)(fb + (size_t)j * K_DIM);
        }
    };
    auto packH = [&](f32x4 (&v)[4], int p) {
        #pragma unroll
        for (int j = 0; j < 4; ++j)
            #pragma unroll
            for (int e = 0; e < 4; ++e)
                trw += v[j][e] * v[j][e];
        #pragma unroll
        for (int e = 0; e < 4; ++e) {
            uint2 pk;
            pk.x = pack_bf16(v[0][e], v[1][e]);
            pk.y = pack_bf16(v[2][e], v[3][e]);
            *(uint2*)&ht[p][(sd * 4 + e) * HT_S + sg * 4] = pk;
        }
    };
    auto packF = [&](int p) {
        if (tid < 256) {
            #pragma unroll
            for (int e = 0; e < 2; ++e) {
                uint2 pk;
                pk.x = pack_bf16(Fw[0][e], Fw[1][e]);
                pk.y = pack_bf16(Fw[2][e], Fw[3][e]);
                *(uint2*)&Ft[p][(fk + e) * HT_S + fg * 4] = pk;
            }
        }
    };
    auto mfmaStep = [&](int c) {
        const int p = c & 1;
        bf16x8 bfrag[2], afrag[4];
        #pragma unroll
        for (int dt = 0; dt < 2; ++dt)
            bfrag[dt] = *(const bf16x8*)&ht[p][(wave * 32 + dt * 16 + m) * HT_S + q * 8];
        #pragma unroll
        for (int kt = 0; kt < 4; ++kt)
            afrag[kt] = *(const bf16x8*)&Ft[p][(kt * 16 + m) * HT_S + q * 8];
        #pragma unroll
        for (int kt = 0; kt < 4; ++kt)
            #pragma unroll
            for (int dt = 0; dt < 2; ++dt)
                acc[kt][dt] = __builtin_amdgcn_mfma_f32_16x16x32_bf16(
                    afrag[kt], bfrag[dt], acc[kt][dt], 0, 0, 0);
    };

    // prologue: chunks 0 and 1 both in flight before first pack
    issueH(0, hA);
    issueH(1, hB);
    issueF(0);
    packF(0);
    packH(hA, 0);

    for (int c = 0; c < nChunks; c += 2) {
        // even iteration: issue -> hA, pack chunk c+1 from hB
        __syncthreads();                          // buf[c&1] holds chunk c
        if (c + 2 < nChunks) issueH(c + 2, hA);
        if (c + 1 < nChunks) issueF(c + 1);
        mfmaStep(c);
        if (c + 1 < nChunks) { packF((c + 1) & 1); packH(hB, (c + 1) & 1); }

        if (c + 1 < nChunks) {                    // odd iteration: roles swapped
            __syncthreads();
            if (c + 3 < nChunks) issueH(c + 3, hB);
            if (c + 2 < nChunks) issueF(c + 2);
            mfmaStep(c + 1);
            if (c + 2 < nChunks) { packF((c + 2) & 1); packH(hA, (c + 2) & 1); }
        }
    }

    // ---- phase-1 epilogue: repack G through LDS, store coalesced ----
    __syncthreads();                              // all frag reads done; ht free
    unsigned short* gt = &ht[0][0];               // 80 KB raw, need 64 KB
    #pragma unroll
    for (int kt = 0; kt < 4; ++kt)
        #pragma unroll
        for (int dt = 0; dt < 2; ++dt)
            #pragma unroll
            for (int r = 0; r < 4; ++r) {
                const int k = kt * 16 + q * 4 + r;      // C/D row = (lane>>4)*4 + reg
                const int d = wave * 32 + dt * 16 + m;  // C/D col = lane&15
                __half hv = __float2half(acc[kt][dt][r]);
                gt[k * D_DIM + d] = *(unsigned short*)&hv;
            }

    #pragma unroll
    for (int off = 32; off > 0; off >>= 1) trw += __shfl_down(trw, off, 64);
    if (lane == 0) red[wave] = trw;
    __syncthreads();                              // gt complete + red complete

    unsigned short* gp = gpart + (size_t)b * GSZ;
    #pragma unroll
    for (int it = 0; it < 4; ++it)
        *(uint4*)(gp + it * 8192 + tid * 8) = *(const uint4*)(gt + it * 8192 + tid * 8);

    if (tid == 0) {
        float s = 0.f;
        #pragma unroll
        for (int w = 0; w < 16; ++w) s += red[w];
        sTrw = s;                                 // block-local; read post-sync by tid 0
    }

    __threadfence();                              // buffer_wbl2: gpart + out[0] visible cross-XCD
    cg::this_grid().sync();

    // ---- phase 2: sum partials over blocks, accumulate -s^2 (+ own trw) ----
    float* sh = (float*)&ht[0][0];                // 32 KB reuse
    const int sub = tid >> 4;                     // 0..63 : b-split
    const int oct = tid & 15;
    const int nOct = GSZ / 8;                     // 4096
    float myVal = 0.f;

    for (int pass = 0; pass < nOct / (P * 16); ++pass) {
        const int tt = pass * P * 16 + b * 16 + oct;
        float g[8];
        #pragma unroll
        for (int j = 0; j < 8; ++j) g[j] = 0.f;
        const unsigned short* base = gpart + (size_t)tt * 8;
        for (int bb = sub; bb < P; bb += 64) {
            half8 v = *(const half8*)(base + (size_t)bb * GSZ);
            #pragma unroll
            for (int j = 0; j < 8; ++j) g[j] += (float)v[j];
        }
        __syncthreads();                          // sh free (prev pass / phase-1 reads done)
        #pragma unroll
        for (int j = 0; j < 8; ++j) sh[(sub * 16 + oct) * 8 + j] = g[j];
        __syncthreads();
        if (tid < 128) {
            const int o2 = tid >> 3, j = tid & 7;
            float s = 0.f;
            #pragma unroll
            for (int sb = 0; sb < 64; ++sb) s += sh[(sb * 16 + o2) * 8 + j];
            myVal += -s * s;
        }
    }
    if (tid == 0) myVal += sTrw;                  // fold this block's tr_wtw partial

    #pragma unroll
    for (int off = 32; off > 0; off >>= 1) myVal += __shfl_down(myVal, off, 64);
    if (lane == 0) red[wave] = myVal;
    __syncthreads();
    if (tid == 0) {
        float s = 0.f;
        #pragma unroll
        for (int w = 0; w < 16; ++w) s += red[w];
        atomicAdd(out, s);
    }
}

// ---------------- fallback path (proven 2-kernel version) ----------------
extern "C" __global__ void __launch_bounds__(1024)
k1_partial(const float* __restrict__ h, const float* __restrict__ F,
           float* __restrict__ trw_out, unsigned short* __restrict__ gpart,
           float* __restrict__ out, int rowsPerBlock) {
    __shared__ unsigned short ht[2][D_DIM * HT_S];
    __shared__ unsigned short Ft[2][K_DIM * HT_S];
    __shared__ float red[16];

    const int tid = threadIdx.x;
    const int b   = blockIdx.x;
    if (b == 0 && tid == 0) out[0] = 0.0f;

    const int row0    = b * rowsPerBlock;
    const int nChunks = rowsPerBlock / NC;

    const int sd = tid & 127;
    const int sg = tid >> 7;
    const int fk = (tid & 31) * 2;
    const int fg = tid >> 5;
    const int wave = tid >> 6;
    const int lane = tid & 63;
    const int m    = lane & 15;
    const int q    = lane >> 4;

    f32x4 acc[4][2];
    #pragma unroll
    for (int kt = 0; kt < 4; ++kt)
        #pragma unroll
        for (int dt = 0; dt < 2; ++dt)
            acc[kt][dt] = (f32x4){0.f, 0.f, 0.f, 0.f};

    float trw = 0.f;

    auto stage = [&](int c, int p) {
        const int r0 = row0 + c * NC;
        const float* hb = h + (size_t)(r0 + sg * 4) * D_DIM + sd * 4;
        f32x4 v[4];
        #pragma unroll
        for (int j = 0; j < 4; ++j)
            v[j] = *(const f32x4*)(hb + (size_t)j * D_DIM);
        #pragma unroll
        for (int j = 0; j < 4; ++j)
            #pragma unroll
            for (int e = 0; e < 4; ++e)
                trw += v[j][e] * v[j][e];
        #pragma unroll
        for (int e = 0; e < 4; ++e) {
            uint2 pk;
            pk.x = pack_bf16(v[0][e], v[1][e]);
            pk.y = pack_bf16(v[2][e], v[3][e]);
            *(uint2*)&ht[p][(sd * 4 + e) * HT_S + sg * 4] = pk;
        }
        if (tid < 256) {
            const float* fb = F + (size_t)(r0 + fg * 4) * K_DIM + fk;
            f32x2 w[4];
            #pragma unroll
            for (int j = 0; j < 4; ++j)
                w[j] = *(const f32x2*)(fb + (size_t)j * K_DIM);
            #pragma unroll
            for (int e = 0; e < 2; ++e) {
                uint2 pk;
                pk.x = pack_bf16(w[0][e], w[1][e]);
                pk.y = pack_bf16(w[2][e], w[3][e]);
                *(uint2*)&Ft[p][(fk + e) * HT_S + fg * 4] = pk;
            }
        }
    };

    stage(0, 0);
    for (int c = 0; c < nChunks; ++c) {
        __syncthreads();
        if (c + 1 < nChunks) stage(c + 1, (c + 1) & 1);
        const int p = c & 1;
        bf16x8 bfrag[2], afrag[4];
        #pragma unroll
        for (int dt = 0; dt < 2; ++dt)
            bfrag[dt] = *(const bf16x8*)&ht[p][(wave * 32 + dt * 16 + m) * HT_S + q * 8];
        #pragma unroll
        for (int kt = 0; kt < 4; ++kt)
            afrag[kt] = *(const bf16x8*)&Ft[p][(kt * 16 + m) * HT_S + q * 8];
        #pragma unroll
        for (int kt = 0; kt < 4; ++kt)
            #pragma unroll
            for (int dt = 0; dt < 2; ++dt)
                acc[kt][dt] = __builtin_amdgcn_mfma_f32_16x16x32_bf16(
                    afrag[kt], bfrag[dt], acc[kt][dt], 0, 0, 0);
    }

    __syncthreads();
    unsigned short* gt = &ht[0][0];
    #pragma unroll
    for (int kt = 0; kt < 4; ++kt)
        #pragma unroll
        for (int dt = 0; dt < 2; ++dt)
            #pragma unroll
            for (int r = 0; r < 4; ++r) {
                const int k = kt * 16 + q * 4 + r;
                const int d = wave * 32 + dt * 16 + m;
                __half hv = __float2half(acc[kt][dt][r]);
                gt[k * D_DIM + d] = *(unsigned short*)&hv;
            }

    #pragma unroll
    for (int off = 32; off > 0; off >>= 1) trw += __shfl_down(trw, off, 64);
    if (lane == 0) red[wave] = trw;
    __syncthreads();

    unsigned short* gp = gpart + (size_t)b * GSZ;
    #pragma unroll
    for (int it = 0; it < 4; ++it)
        *(uint4*)(gp + it * 8192 + tid * 8) = *(const uint4*)(gt + it * 8192 + tid * 8);

    if (tid == 0) {
        float s = 0.f;
        #pragma unroll
        for (int w = 0; w < 16; ++w) s += red[w];
        trw_out[b] = s;
    }
}

extern "C" __global__ void __launch_bounds__(512)
k2_reduce(const float* __restrict__ trw, const unsigned short* __restrict__ gpart,
          float* __restrict__ out, int P) {
    __shared__ float sh[32 * 16 * 8];
    __shared__ float red2[8];

    const int tid = threadIdx.x;
    const int sub = tid >> 4;
    const int oct = tid & 15;
    const int tt  = blockIdx.x * 16 + oct;

    float g[8];
    #pragma unroll
    for (int j = 0; j < 8; ++j) g[j] = 0.f;

    const unsigned short* base = gpart + (size_t)tt * 8;
    for (int b = sub; b < P; b += 32) {
        half8 v = *(const half8*)(base + (size_t)b * GSZ);
        #pragma unroll
        for (int j = 0; j < 8; ++j) g[j] += (float)v[j];
    }
    #pragma unroll
    for (int j = 0; j < 8; ++j) sh[(sub * 16 + oct) * 8 + j] = g[j];
    __syncthreads();

    float val = 0.f;
    if (tid < 128) {
        const int o2 = tid >> 3, j = tid & 7;
        float s = 0.f;
        #pragma unroll
        for (int sb = 0; sb < 32; ++sb) s += sh[(sb * 16 + o2) * 8 + j];
        val = -s * s;
    } else if (blockIdx.x == 0 && tid - 128 < P) {
        val = trw[tid - 128];
    }

    #pragma unroll
    for (int off = 32; off > 0; off >>= 1) val += __shfl_down(val, off, 64);
    if ((tid & 63) == 0) red2[tid >> 6] = val;
    __syncthreads();
    if (tid == 0) {
        float s = 0.f;
        #pragma unroll
        for (int w = 0; w < 8; ++w) s += red2[w];
        atomicAdd(out, s);
    }
}

extern "C" void kernel_launch(void* const* d_in, const int* in_sizes, int n_in,
                              void* d_out, int out_size, void* d_ws, size_t ws_size,
                              hipStream_t stream) {
    const float* h = (const float*)d_in[0];   // [65536, 512]
    const float* F = (const float*)d_in[1];   // [65536, 64]
    float* out = (float*)d_out;

    // ws layout: [0,4096): trw fp32 (fallback) ; [4096, 4096+P*64KiB): fp16 partial G
    int P = 256;
    while (P > 1 && (size_t)4096 + (size_t)P * (GSZ * 2) > ws_size) P >>= 1;
    int rowsPerBlock = N_TOT / P;

    float* trw = (float*)d_ws;
    unsigned short* gpart = (unsigned short*)((char*)d_ws + 4096);

    void* args[6];
    args[0] = (void*)&h;
    args[1] = (void*)&F;
    args[2] = (void*)&gpart;
    args[3] = (void*)&out;
    args[4] = (void*)&rowsPerBlock;
    args[5] = (void*)&P;

    hipError_t e = hipLaunchCooperativeKernel((const void*)fused, dim3(P), dim3(1024),
                                              args, 0, stream);
    if (e != hipSuccess) {
        hipLaunchKernelGGL(k1_partial, dim3(P), dim3(1024), 0, stream,
                           h, F, trw, gpart, out, rowsPerBlock);
        hipLaunchKernelGGL(k2_reduce, dim3(256), dim3(512), 0, stream,
                           trw, gpart, out, P);
    }
}

// Round 3
// 354.641 us; speedup vs baseline: 1.0001x; 1.0001x over previous
//
#include <hip/hip_runtime.h>
#include <hip/hip_fp16.h>
#include <hip/hip_cooperative_groups.h>

namespace cg = cooperative_groups;

#define N_TOT 65536
#define D_DIM 512
#define K_DIM 64
#define NC    32          // n-rows per chunk (one MFMA K=32 step)
#define HT_S  40          // LDS row stride in bf16 elems = 80 B (16B-aligned rows)
#define GSZ   (K_DIM * D_DIM)   // 32768 elements of partial G

typedef __bf16   bf16x8 __attribute__((ext_vector_type(8)));
typedef float    f32x4  __attribute__((ext_vector_type(4)));
typedef float    f32x2  __attribute__((ext_vector_type(2)));
typedef _Float16 half8  __attribute__((ext_vector_type(8)));

__device__ __forceinline__ unsigned int pack_bf16(float a, float b) {
    union { float f; unsigned int u; } x, y;
    x.f = a; y.f = b;
    unsigned int lo = (x.u + 0x7fffu + ((x.u >> 16) & 1u)) >> 16;   // RNE
    unsigned int hi = (y.u + 0x7fffu + ((y.u >> 16) & 1u)) >> 16;
    return lo | (hi << 16);
}

// Fused cooperative kernel, v3.
// R2 post-mortem: T14 reg-double-buffer + default __launch_bounds__(1024) capped
// VGPRs at 64 -> compiler serialized loads by reusing dest regs (1 load in
// flight/wave -> 508 GB/s, 198 us). Fix: (a) revert to the R0/R1-proven
// stage-after-barrier structure (loads transient inside stage()); (b)
// __launch_bounds__(1024, 4): LDS (92.7 KB) forces 1 block/CU anyway, so
// declaring 4 waves/EU lifts the VGPR cap for free -> full MLP restored.
extern "C" __global__ void __launch_bounds__(1024, 4)
fused(const float* __restrict__ h, const float* __restrict__ F,
      unsigned short* __restrict__ gpart, float* __restrict__ out,
      int rowsPerBlock, int P) {
    __shared__ unsigned short ht[2][D_DIM * HT_S];   // 2 x 40960 B, ht[d][n]
    __shared__ unsigned short Ft[2][K_DIM * HT_S];   // 2 x  5120 B, Ft[k][n]
    __shared__ float red[16];
    __shared__ float sTrw;

    const int tid = threadIdx.x;
    const int b   = blockIdx.x;
    if (b == 0 && tid == 0) out[0] = 0.0f;    // visible after grid.sync (fence below)

    const int row0    = b * rowsPerBlock;
    const int nChunks = rowsPerBlock / NC;

    // staging ids (h): lane owns d-quad; sg picks 4-row n-group
    const int sd = tid & 127;
    const int sg = tid >> 7;
    // staging ids (F): threads 0..255
    const int fk = (tid & 31) * 2;
    const int fg = tid >> 5;
    // mfma ids
    const int wave = tid >> 6;
    const int lane = tid & 63;
    const int m    = lane & 15;
    const int q    = lane >> 4;

    f32x4 acc[4][2];
    #pragma unroll
    for (int kt = 0; kt < 4; ++kt)
        #pragma unroll
        for (int dt = 0; dt < 2; ++dt)
            acc[kt][dt] = (f32x4){0.f, 0.f, 0.f, 0.f};

    float trw = 0.f;

    auto stage = [&](int c, int p) {
        const int r0 = row0 + c * NC;
        const float* hb = h + (size_t)(r0 + sg * 4) * D_DIM + sd * 4;
        f32x4 v[4];
        #pragma unroll
        for (int j = 0; j < 4; ++j)
            v[j] = *(const f32x4*)(hb + (size_t)j * D_DIM);
        #pragma unroll
        for (int j = 0; j < 4; ++j)
            #pragma unroll
            for (int e = 0; e < 4; ++e)
                trw += v[j][e] * v[j][e];
        #pragma unroll
        for (int e = 0; e < 4; ++e) {
            uint2 pk;
            pk.x = pack_bf16(v[0][e], v[1][e]);
            pk.y = pack_bf16(v[2][e], v[3][e]);
            *(uint2*)&ht[p][(sd * 4 + e) * HT_S + sg * 4] = pk;
        }
        if (tid < 256) {
            const float* fb = F + (size_t)(r0 + fg * 4) * K_DIM + fk;
            f32x2 w[4];
            #pragma unroll
            for (int j = 0; j < 4; ++j)
                w[j] = *(const f32x2*)(fb + (size_t)j * K_DIM);
            #pragma unroll
            for (int e = 0; e < 2; ++e) {
                uint2 pk;
                pk.x = pack_bf16(w[0][e], w[1][e]);
                pk.y = pack_bf16(w[2][e], w[3][e]);
                *(uint2*)&Ft[p][(fk + e) * HT_S + fg * 4] = pk;
            }
        }
    };

    stage(0, 0);   // prologue

    for (int c = 0; c < nChunks; ++c) {
        __syncthreads();                          // buf[c&1] ready; other buf free
        if (c + 1 < nChunks) stage(c + 1, (c + 1) & 1);

        const int p = c & 1;
        bf16x8 bfrag[2], afrag[4];
        #pragma unroll
        for (int dt = 0; dt < 2; ++dt)
            bfrag[dt] = *(const bf16x8*)&ht[p][(wave * 32 + dt * 16 + m) * HT_S + q * 8];
        #pragma unroll
        for (int kt = 0; kt < 4; ++kt)
            afrag[kt] = *(const bf16x8*)&Ft[p][(kt * 16 + m) * HT_S + q * 8];
        #pragma unroll
        for (int kt = 0; kt < 4; ++kt)
            #pragma unroll
            for (int dt = 0; dt < 2; ++dt)
                acc[kt][dt] = __builtin_amdgcn_mfma_f32_16x16x32_bf16(
                    afrag[kt], bfrag[dt], acc[kt][dt], 0, 0, 0);
    }

    // ---- phase-1 epilogue: repack G through LDS, store coalesced ----
    __syncthreads();                              // all frag reads done; ht free
    unsigned short* gt = &ht[0][0];               // 80 KB raw, need 64 KB
    #pragma unroll
    for (int kt = 0; kt < 4; ++kt)
        #pragma unroll
        for (int dt = 0; dt < 2; ++dt)
            #pragma unroll
            for (int r = 0; r < 4; ++r) {
                const int k = kt * 16 + q * 4 + r;      // C/D row = (lane>>4)*4 + reg
                const int d = wave * 32 + dt * 16 + m;  // C/D col = lane&15
                __half hv = __float2half(acc[kt][dt][r]);
                gt[k * D_DIM + d] = *(unsigned short*)&hv;
            }

    #pragma unroll
    for (int off = 32; off > 0; off >>= 1) trw += __shfl_down(trw, off, 64);
    if (lane == 0) red[wave] = trw;
    __syncthreads();                              // gt complete + red complete

    unsigned short* gp = gpart + (size_t)b * GSZ;
    #pragma unroll
    for (int it = 0; it < 4; ++it)
        *(uint4*)(gp + it * 8192 + tid * 8) = *(const uint4*)(gt + it * 8192 + tid * 8);

    if (tid == 0) {
        float s = 0.f;
        #pragma unroll
        for (int w = 0; w < 16; ++w) s += red[w];
        sTrw = s;                                 // block-local; read post-sync by tid 0
    }

    __threadfence();                              // flush gpart + out[0] device-scope
    cg::this_grid().sync();

    // ---- phase 2: sum partials over blocks, accumulate -s^2 (+ own trw) ----
    float* sh = (float*)&ht[0][0];                // 32 KB reuse
    const int sub = tid >> 4;                     // 0..63 : b-split
    const int oct = tid & 15;
    const int nOct = GSZ / 8;                     // 4096
    float myVal = 0.f;

    for (int pass = 0; pass < nOct / (P * 16); ++pass) {
        const int tt = pass * P * 16 + b * 16 + oct;
        float g[8];
        #pragma unroll
        for (int j = 0; j < 8; ++j) g[j] = 0.f;
        const unsigned short* base = gpart + (size_t)tt * 8;
        for (int bb = sub; bb < P; bb += 64) {
            half8 v = *(const half8*)(base + (size_t)bb * GSZ);
            #pragma unroll
            for (int j = 0; j < 8; ++j) g[j] += (float)v[j];
        }
        __syncthreads();                          // sh free
        #pragma unroll
        for (int j = 0; j < 8; ++j) sh[(sub * 16 + oct) * 8 + j] = g[j];
        __syncthreads();
        if (tid < 128) {
            const int o2 = tid >> 3, j = tid & 7;
            float s = 0.f;
            #pragma unroll
            for (int sb = 0; sb < 64; ++sb) s += sh[(sb * 16 + o2) * 8 + j];
            myVal += -s * s;
        }
    }
    if (tid == 0) myVal += sTrw;                  // fold this block's tr_wtw partial

    #pragma unroll
    for (int off = 32; off > 0; off >>= 1) myVal += __shfl_down(myVal, off, 64);
    if (lane == 0) red[wave] = myVal;
    __syncthreads();
    if (tid == 0) {
        float s = 0.f;
        #pragma unroll
        for (int w = 0; w < 16; ++w) s += red[w];
        atomicAdd(out, s);
    }
}

// ---------------- fallback path (proven 2-kernel version) ----------------
extern "C" __global__ void __launch_bounds__(1024, 4)
k1_partial(const float* __restrict__ h, const float* __restrict__ F,
           float* __restrict__ trw_out, unsigned short* __restrict__ gpart,
           float* __restrict__ out, int rowsPerBlock) {
    __shared__ unsigned short ht[2][D_DIM * HT_S];
    __shared__ unsigned short Ft[2][K_DIM * HT_S];
    __shared__ float red[16];

    const int tid = threadIdx.x;
    const int b   = blockIdx.x;
    if (b == 0 && tid == 0) out[0] = 0.0f;

    const int row0    = b * rowsPerBlock;
    const int nChunks = rowsPerBlock / NC;

    const int sd = tid & 127;
    const int sg = tid >> 7;
    const int fk = (tid & 31) * 2;
    const int fg = tid >> 5;
    const int wave = tid >> 6;
    const int lane = tid & 63;
    const int m    = lane & 15;
    const int q    = lane >> 4;

    f32x4 acc[4][2];
    #pragma unroll
    for (int kt = 0; kt < 4; ++kt)
        #pragma unroll
        for (int dt = 0; dt < 2; ++dt)
            acc[kt][dt] = (f32x4){0.f, 0.f, 0.f, 0.f};

    float trw = 0.f;

    auto stage = [&](int c, int p) {
        const int r0 = row0 + c * NC;
        const float* hb = h + (size_t)(r0 + sg * 4) * D_DIM + sd * 4;
        f32x4 v[4];
        #pragma unroll
        for (int j = 0; j < 4; ++j)
            v[j] = *(const f32x4*)(hb + (size_t)j * D_DIM);
        #pragma unroll
        for (int j = 0; j < 4; ++j)
            #pragma unroll
            for (int e = 0; e < 4; ++e)
                trw += v[j][e] * v[j][e];
        #pragma unroll
        for (int e = 0; e < 4; ++e) {
            uint2 pk;
            pk.x = pack_bf16(v[0][e], v[1][e]);
            pk.y = pack_bf16(v[2][e], v[3][e]);
            *(uint2*)&ht[p][(sd * 4 + e) * HT_S + sg * 4] = pk;
        }
        if (tid < 256) {
            const float* fb = F + (size_t)(r0 + fg * 4) * K_DIM + fk;
            f32x2 w[4];
            #pragma unroll
            for (int j = 0; j < 4; ++j)
                w[j] = *(const f32x2*)(fb + (size_t)j * K_DIM);
            #pragma unroll
            for (int e = 0; e < 2; ++e) {
                uint2 pk;
                pk.x = pack_bf16(w[0][e], w[1][e]);
                pk.y = pack_bf16(w[2][e], w[3][e]);
                *(uint2*)&Ft[p][(fk + e) * HT_S + fg * 4] = pk;
            }
        }
    };

    stage(0, 0);
    for (int c = 0; c < nChunks; ++c) {
        __syncthreads();
        if (c + 1 < nChunks) stage(c + 1, (c + 1) & 1);
        const int p = c & 1;
        bf16x8 bfrag[2], afrag[4];
        #pragma unroll
        for (int dt = 0; dt < 2; ++dt)
            bfrag[dt] = *(const bf16x8*)&ht[p][(wave * 32 + dt * 16 + m) * HT_S + q * 8];
        #pragma unroll
        for (int kt = 0; kt < 4; ++kt)
            afrag[kt] = *(const bf16x8*)&Ft[p][(kt * 16 + m) * HT_S + q * 8];
        #pragma unroll
        for (int kt = 0; kt < 4; ++kt)
            #pragma unroll
            for (int dt = 0; dt < 2; ++dt)
                acc[kt][dt] = __builtin_amdgcn_mfma_f32_16x16x32_bf16(
                    afrag[kt], bfrag[dt], acc[kt][dt], 0, 0, 0);
    }

    __syncthreads();
    unsigned short* gt = &ht[0][0];
    #pragma unroll
    for (int kt = 0; kt < 4; ++kt)
        #pragma unroll
        for (int dt = 0; dt < 2; ++dt)
            #pragma unroll
            for (int r = 0; r < 4; ++r) {
                const int k = kt * 16 + q * 4 + r;
                const int d = wave * 32 + dt * 16 + m;
                __half hv = __float2half(acc[kt][dt][r]);
                gt[k * D_DIM + d] = *(unsigned short*)&hv;
            }

    #pragma unroll
    for (int off = 32; off > 0; off >>= 1) trw += __shfl_down(trw, off, 64);
    if (lane == 0) red[wave] = trw;
    __syncthreads();

    unsigned short* gp = gpart + (size_t)b * GSZ;
    #pragma unroll
    for (int it = 0; it < 4; ++it)
        *(uint4*)(gp + it * 8192 + tid * 8) = *(const uint4*)(gt + it * 8192 + tid * 8);

    if (tid == 0) {
        float s = 0.f;
        #pragma unroll
        for (int w = 0; w < 16; ++w) s += red[w];
        trw_out[b] = s;
    }
}

extern "C" __global__ void __launch_bounds__(512)
k2_reduce(const float* __restrict__ trw, const unsigned short* __restrict__ gpart,
          float* __restrict__ out, int P) {
    __shared__ float sh[32 * 16 * 8];
    __shared__ float red2[8];

    const int tid = threadIdx.x;
    const int sub = tid >> 4;
    const int oct = tid & 15;
    const int tt  = blockIdx.x * 16 + oct;

    float g[8];
    #pragma unroll
    for (int j = 0; j < 8; ++j) g[j] = 0.f;

    const unsigned short* base = gpart + (size_t)tt * 8;
    for (int b = sub; b < P; b += 32) {
        half8 v = *(const half8*)(base + (size_t)b * GSZ);
        #pragma unroll
        for (int j = 0; j < 8; ++j) g[j] += (float)v[j];
    }
    #pragma unroll
    for (int j = 0; j < 8; ++j) sh[(sub * 16 + oct) * 8 + j] = g[j];
    __syncthreads();

    float val = 0.f;
    if (tid < 128) {
        const int o2 = tid >> 3, j = tid & 7;
        float s = 0.f;
        #pragma unroll
        for (int sb = 0; sb < 32; ++sb) s += sh[(sb * 16 + o2) * 8 + j];
        val = -s * s;
    } else if (blockIdx.x == 0 && tid - 128 < P) {
        val = trw[tid - 128];
    }

    #pragma unroll
    for (int off = 32; off > 0; off >>= 1) val += __shfl_down(val, off, 64);
    if ((tid & 63) == 0) red2[tid >> 6] = val;
    __syncthreads();
    if (tid == 0) {
        float s = 0.f;
        #pragma unroll
        for (int w = 0; w < 8; ++w) s += red2[w];
        atomicAdd(out, s);
    }
}

extern "C" void kernel_launch(void* const* d_in, const int* in_sizes, int n_in,
                              void* d_out, int out_size, void* d_ws, size_t ws_size,
                              hipStream_t stream) {
    const float* h = (const float*)d_in[0];   // [65536, 512]
    const float* F = (const float*)d_in[1];   // [65536, 64]
    float* out = (float*)d_out;

    // ws layout: [0,4096): trw fp32 (fallback) ; [4096, 4096+P*64KiB): fp16 partial G
    int P = 256;
    while (P > 1 && (size_t)4096 + (size_t)P * (GSZ * 2) > ws_size) P >>= 1;
    int rowsPerBlock = N_TOT / P;

    float* trw = (float*)d_ws;
    unsigned short* gpart = (unsigned short*)((char*)d_ws + 4096);

    void* args[6];
    args[0] = (void*)&h;
    args[1] = (void*)&F;
    args[2] = (void*)&gpart;
    args[3] = (void*)&out;
    args[4] = (void*)&rowsPerBlock;
    args[5] = (void*)&P;

    hipError_t e = hipLaunchCooperativeKernel((const void*)fused, dim3(P), dim3(1024),
                                              args, 0, stream);
    if (e != hipSuccess) {
        hipLaunchKernelGGL(k1_partial, dim3(P), dim3(1024), 0, stream,
                           h, F, trw, gpart, out, rowsPerBlock);
        hipLaunchKernelGGL(k2_reduce, dim3(256), dim3(512), 0, stream,
                           trw, gpart, out, P);
    }
}

// Round 4
// 212.019 us; speedup vs baseline: 1.6729x; 1.6727x over previous
//
#include <hip/hip_runtime.h>
#include <hip/hip_fp16.h>

#define N_TOT 65536
#define D_DIM 512
#define K_DIM 64
#define NC    32          // n-rows per chunk (one MFMA K=32 step)
#define HT_S  40          // LDS row stride in bf16 elems = 80 B (16B-aligned rows)
#define GSZ   (K_DIM * D_DIM)   // 32768 elements of partial G

typedef __bf16   bf16x8 __attribute__((ext_vector_type(8)));
typedef float    f32x4  __attribute__((ext_vector_type(4)));
typedef _Float16 half8  __attribute__((ext_vector_type(8)));

__device__ __forceinline__ unsigned int pack_bf16(float a, float b) {
    union { float f; unsigned int u; } x, y;
    x.f = a; y.f = b;
    unsigned int lo = (x.u + 0x7fffu + ((x.u >> 16) & 1u)) >> 16;   // RNE
    unsigned int hi = (y.u + 0x7fffu + ((y.u >> 16) & 1u)) >> 16;
    return lo | (hi << 16);
}

// K1 v4. R2/R3 post-mortem: cooperative fusion cost ~150us in grid.sync spin ->
// reverted to the proven 2-kernel structure (R1, 210-212us total).
// v4 change vs R1: frags-FIRST chunk body. Old order (stage -> vmcnt-wait ->
// pack -> ds_write -> ds_read -> MFMA) serialized every chunk's LDS+MFMA tail
// behind the global-load drain (compiler can't hoist ds_read(ht[p]) above
// ds_write(ht[p^1]) without an LDS alias proof). New order:
//   barrier -> ds_read frags(c) -> issue c+1 global loads -> MFMA(c)
//   -> vmcnt wait -> pack(c+1) -> barrier
// so loads stay in flight across the whole MFMA+pack region of every chunk.
// __launch_bounds__(1024,4): LDS (92.7KB) forces 1 block/CU anyway; declaring
// 4 waves/EU lifts the VGPR cap to 128 so in-flight loads (24) + frags (24) +
// acc (32) coexist without degrading load MLP.
extern "C" __global__ void __launch_bounds__(1024, 4)
k1_partial(const float* __restrict__ h, const float* __restrict__ F,
           float* __restrict__ trw_out, unsigned short* __restrict__ gpart,
           float* __restrict__ out, int rowsPerBlock) {
    __shared__ unsigned short ht[2][D_DIM * HT_S];   // 2 x 40960 B, ht[d][n]
    __shared__ unsigned short Ft[2][K_DIM * HT_S];   // 2 x  5120 B, Ft[k][n]
    __shared__ float red[16];

    const int tid = threadIdx.x;
    const int b   = blockIdx.x;
    if (b == 0 && tid == 0) out[0] = 0.0f;        // d_out poisoned; zero before K2

    const int row0    = b * rowsPerBlock;
    const int nChunks = rowsPerBlock / NC;

    // staging ids (h): lane owns d-quad; sg picks 4-row n-group
    const int sd = tid & 127;
    const int sg = tid >> 7;
    // staging ids (F): threads 0..255; lane owns k-quad, fg picks row-pair
    const int fk = (tid & 15) * 4;     // k-quad base
    const int fg = (tid >> 4) & 15;    // row-pair 0..15 (rows fg*2, fg*2+1)
    // mfma ids
    const int wave = tid >> 6;
    const int lane = tid & 63;
    const int m    = lane & 15;
    const int q    = lane >> 4;

    f32x4 acc[4][2];
    #pragma unroll
    for (int kt = 0; kt < 4; ++kt)
        #pragma unroll
        for (int dt = 0; dt < 2; ++dt)
            acc[kt][dt] = (f32x4){0.f, 0.f, 0.f, 0.f};

    float trw = 0.f;
    f32x4 v[4];          // in-flight h rows for next chunk
    f32x4 w0, w1;        // in-flight F rows for next chunk

    auto issue = [&](int c) {
        const int r0 = row0 + c * NC;
        const float* hb = h + (size_t)(r0 + sg * 4) * D_DIM + sd * 4;
        #pragma unroll
        for (int j = 0; j < 4; ++j)
            v[j] = *(const f32x4*)(hb + (size_t)j * D_DIM);
        if (tid < 256) {
            const float* fb = F + (size_t)(r0 + fg * 2) * K_DIM + fk;
            w0 = *(const f32x4*)fb;
            w1 = *(const f32x4*)(fb + K_DIM);
        }
    };
    auto pack = [&](int p) {
        #pragma unroll
        for (int j = 0; j < 4; ++j)
            #pragma unroll
            for (int e = 0; e < 4; ++e)
                trw += v[j][e] * v[j][e];
        #pragma unroll
        for (int e = 0; e < 4; ++e) {
            uint2 pk;
            pk.x = pack_bf16(v[0][e], v[1][e]);
            pk.y = pack_bf16(v[2][e], v[3][e]);
            *(uint2*)&ht[p][(sd * 4 + e) * HT_S + sg * 4] = pk;
        }
        if (tid < 256) {
            #pragma unroll
            for (int e = 0; e < 4; ++e) {
                unsigned int pk = pack_bf16(w0[e], w1[e]);
                *(unsigned int*)&Ft[p][(fk + e) * HT_S + fg * 2] = pk;
            }
        }
    };

    issue(0); pack(0);                            // prologue: chunk 0 staged

    for (int c = 0; c < nChunks; ++c) {
        __syncthreads();                          // buf[c&1] ready; other buf free
        const int p = c & 1;

        // 1) LDS frag reads of current chunk (issue before any new ds_write)
        bf16x8 bfrag[2], afrag[4];
        #pragma unroll
        for (int dt = 0; dt < 2; ++dt)
            bfrag[dt] = *(const bf16x8*)&ht[p][(wave * 32 + dt * 16 + m) * HT_S + q * 8];
        #pragma unroll
        for (int kt = 0; kt < 4; ++kt)
            afrag[kt] = *(const bf16x8*)&Ft[p][(kt * 16 + m) * HT_S + q * 8];

        // 2) issue next chunk's global loads (no wait — in flight across MFMA)
        if (c + 1 < nChunks) issue(c + 1);

        // 3) MFMA on current frags (register-only; waits lgkmcnt, not vmcnt)
        #pragma unroll
        for (int kt = 0; kt < 4; ++kt)
            #pragma unroll
            for (int dt = 0; dt < 2; ++dt)
                acc[kt][dt] = __builtin_amdgcn_mfma_f32_16x16x32_bf16(
                    afrag[kt], bfrag[dt], acc[kt][dt], 0, 0, 0);

        // 4) drain loads, pack into the other buffer
        if (c + 1 < nChunks) pack((c + 1) & 1);
    }

    // ---- epilogue: repack G through LDS, store coalesced ----
    __syncthreads();                              // all frag reads done; ht free
    unsigned short* gt = &ht[0][0];               // 80 KB raw, need 64 KB
    #pragma unroll
    for (int kt = 0; kt < 4; ++kt)
        #pragma unroll
        for (int dt = 0; dt < 2; ++dt)
            #pragma unroll
            for (int r = 0; r < 4; ++r) {
                const int k = kt * 16 + q * 4 + r;      // C/D row = (lane>>4)*4 + reg
                const int d = wave * 32 + dt * 16 + m;  // C/D col = lane&15
                __half hv = __float2half(acc[kt][dt][r]);
                gt[k * D_DIM + d] = *(unsigned short*)&hv;
            }

    #pragma unroll
    for (int off = 32; off > 0; off >>= 1) trw += __shfl_down(trw, off, 64);
    if (lane == 0) red[wave] = trw;
    __syncthreads();                              // gt complete + red complete

    unsigned short* gp = gpart + (size_t)b * GSZ;
    #pragma unroll
    for (int it = 0; it < 4; ++it)                // 32768 u16 / 1024 thr = 4x 16B
        *(uint4*)(gp + it * 8192 + tid * 8) = *(const uint4*)(gt + it * 8192 + tid * 8);

    if (tid == 0) {
        float s = 0.f;
        #pragma unroll
        for (int w = 0; w < 16; ++w) s += red[w];
        trw_out[b] = s;
    }
}

// K2: out = sum_b trw[b] - sum_{k,d} (sum_b Gpart[b][k,d])^2   (unchanged, proven)
extern "C" __global__ void __launch_bounds__(512)
k2_reduce(const float* __restrict__ trw, const unsigned short* __restrict__ gpart,
          float* __restrict__ out, int P) {
    __shared__ float sh[32 * 16 * 8];   // 16 KB: [sub][oct][j]
    __shared__ float red2[8];

    const int tid = threadIdx.x;
    const int sub = tid >> 4;                  // 0..31 : b-split
    const int oct = tid & 15;
    const int tt  = blockIdx.x * 16 + oct;     // 0..4095 ; elements 8tt..8tt+7

    float g[8];
    #pragma unroll
    for (int j = 0; j < 8; ++j) g[j] = 0.f;

    const unsigned short* base = gpart + (size_t)tt * 8;
    for (int b = sub; b < P; b += 32) {
        half8 v = *(const half8*)(base + (size_t)b * GSZ);
        #pragma unroll
        for (int j = 0; j < 8; ++j) g[j] += (float)v[j];
    }
    #pragma unroll
    for (int j = 0; j < 8; ++j) sh[(sub * 16 + oct) * 8 + j] = g[j];
    __syncthreads();

    float val = 0.f;
    if (tid < 128) {
        const int o2 = tid >> 3, j = tid & 7;
        float s = 0.f;
        #pragma unroll
        for (int sb = 0; sb < 32; ++sb) s += sh[(sb * 16 + o2) * 8 + j];
        val = -s * s;
    } else if (blockIdx.x == 0 && tid - 128 < P) {
        val = trw[tid - 128];                  // fold tr_wtw partials in block 0
    }

    #pragma unroll
    for (int off = 32; off > 0; off >>= 1) val += __shfl_down(val, off, 64);
    if ((tid & 63) == 0) red2[tid >> 6] = val;
    __syncthreads();
    if (tid == 0) {
        float s = 0.f;
        #pragma unroll
        for (int w = 0; w < 8; ++w) s += red2[w];
        atomicAdd(out, s);
    }
}

extern "C" void kernel_launch(void* const* d_in, const int* in_sizes, int n_in,
                              void* d_out, int out_size, void* d_ws, size_t ws_size,
                              hipStream_t stream) {
    const float* h = (const float*)d_in[0];   // [65536, 512]
    const float* F = (const float*)d_in[1];   // [65536, 64]
    float* out = (float*)d_out;

    // ws layout: [0,4096): trw fp32 (P<=256) ; [4096, 4096+P*64KiB): fp16 partial G
    int P = 256;
    while (P > 1 && (size_t)4096 + (size_t)P * (GSZ * 2) > ws_size) P >>= 1;
    const int rowsPerBlock = N_TOT / P;

    float* trw = (float*)d_ws;
    unsigned short* gpart = (unsigned short*)((char*)d_ws + 4096);

    hipLaunchKernelGGL(k1_partial, dim3(P), dim3(1024), 0, stream,
                       h, F, trw, gpart, out, rowsPerBlock);
    hipLaunchKernelGGL(k2_reduce, dim3(256), dim3(512), 0, stream,
                       trw, gpart, out, P);
}

// Round 5
// 211.125 us; speedup vs baseline: 1.6800x; 1.0042x over previous
//
#include <hip/hip_runtime.h>
#include <hip/hip_fp16.h>

#define N_TOT 65536
#define D_DIM 512
#define K_DIM 64
#define FT_S  264         // Ft row stride (bf16 elems), 528 B: afrag ds_read_b128
                          //   bank = (4*(m+q) + 16c) % 32 -> exact 8-phase, conflict-free
#define GSZ   (K_DIM * D_DIM)   // 32768 elements of partial G

typedef __bf16   bf16x8 __attribute__((ext_vector_type(8)));
typedef float    f32x4  __attribute__((ext_vector_type(4)));
typedef _Float16 half8  __attribute__((ext_vector_type(8)));

__device__ __forceinline__ unsigned int pack_bf16(float a, float b) {
    union { float f; unsigned int u; } x, y;
    x.f = a; y.f = b;
    unsigned int lo = (x.u + 0x7fffu + ((x.u >> 16) & 1u)) >> 16;   // RNE
    unsigned int hi = (y.u + 0x7fffu + ((y.u >> 16) & 1u)) >> 16;
    return lo | (hi << 16);
}

// K1 v5: BARRIER-FREE main loop.
// R0/R1/R4 post-mortem: three different staging structures inside the
// barrier-lockstep regime all gave identical totals -> the lockstep itself is
// the suspect. h has ZERO cross-wave reuse (wave w owns d-slice [32w,32w+32)),
// so LDS-staging h bought nothing and cost 2 barriers/chunk. v5:
//   - F (the only shared operand) staged to LDS ONCE per 256-row superchunk.
//   - h MFMA B-fragments loaded global->reg directly: per chunk/wave 16 scalar
//     dwords; lanes m=0..15 form 64B segments, dt=0/1 covers both halves of
//     each 128B line within the same wave -> full line utilization.
//   - 8 chunks run with NO __syncthreads: 16 independent waves/CU keep the
//     VMEM queue full continuously (no lockstep drain).
extern "C" __global__ void __launch_bounds__(1024, 4)
k1_partial(const float* __restrict__ h, const float* __restrict__ F,
           float* __restrict__ trw_out, unsigned short* __restrict__ gpart,
           float* __restrict__ out, int rowsPerBlock) {
    __shared__ unsigned short Ft[K_DIM * FT_S];   // 33792 B, Ft[k][n], n=0..255
    __shared__ unsigned short gt[GSZ];            // 65536 B, epilogue repack
    __shared__ float red[16];

    const int tid = threadIdx.x;
    const int b   = blockIdx.x;
    if (b == 0 && tid == 0) out[0] = 0.0f;        // d_out poisoned; zero before K2

    const int wave = tid >> 6;                    // 0..15 ; wave owns d in [32w,32w+32)
    const int lane = tid & 63;
    const int m    = lane & 15;
    const int q    = lane >> 4;
    const int d0   = wave * 32 + m;

    f32x4 acc[4][2];
    #pragma unroll
    for (int kt = 0; kt < 4; ++kt)
        #pragma unroll
        for (int dt = 0; dt < 2; ++dt)
            acc[kt][dt] = (f32x4){0.f, 0.f, 0.f, 0.f};

    float trw = 0.f;

    const int nSuper = rowsPerBlock >> 8;         // 256-row superchunks (P=256 -> 1)
    for (int sc = 0; sc < nSuper; ++sc) {
        const int n0 = b * rowsPerBlock + sc * 256;

        // ---- stage Ft: 256 rows x 64 k, fp32 -> bf16, once per superchunk ----
        if (sc) __syncthreads();                  // prior superchunk's reads done
        {
            const int fk = (tid & 15) * 4;        // k-quad
            const int fr = (tid >> 4) & 15;       // row-pair within 32-row slice
            const int sl = tid >> 8;              // 0..3 -> slices sl, sl+4
            #pragma unroll
            for (int ss = 0; ss < 2; ++ss) {
                const int n = (sl + ss * 4) * 32 + fr * 2;
                const float* fb = F + (size_t)(n0 + n) * K_DIM + fk;
                f32x4 w0 = *(const f32x4*)fb;
                f32x4 w1 = *(const f32x4*)(fb + K_DIM);
                #pragma unroll
                for (int e = 0; e < 4; ++e)
                    *(unsigned int*)&Ft[(fk + e) * FT_S + n] = pack_bf16(w0[e], w1[e]);
            }
        }
        __syncthreads();                          // Ft ready; no barriers for 8 chunks

        for (int c = 0; c < 8; ++c) {
            const int nb = n0 + c * 32 + q * 8;
            // h fragments: global -> reg (column of 8 n's per dt half)
            float v[2][8];
            #pragma unroll
            for (int dt = 0; dt < 2; ++dt) {
                const float* hb = h + (size_t)nb * D_DIM + d0 + dt * 16;
                #pragma unroll
                for (int j = 0; j < 8; ++j)
                    v[dt][j] = hb[(size_t)j * D_DIM];
            }
            // F fragments from LDS (conflict-free b128)
            bf16x8 afrag[4];
            #pragma unroll
            for (int kt = 0; kt < 4; ++kt)
                afrag[kt] = *(const bf16x8*)&Ft[(kt * 16 + m) * FT_S + c * 32 + q * 8];
            // convert h to bf16 + fold trw
            bf16x8 bfrag[2];
            #pragma unroll
            for (int dt = 0; dt < 2; ++dt) {
                uint4 pk;
                pk.x = pack_bf16(v[dt][0], v[dt][1]);
                pk.y = pack_bf16(v[dt][2], v[dt][3]);
                pk.z = pack_bf16(v[dt][4], v[dt][5]);
                pk.w = pack_bf16(v[dt][6], v[dt][7]);
                bfrag[dt] = *(bf16x8*)&pk;
                #pragma unroll
                for (int j = 0; j < 8; ++j)
                    trw += v[dt][j] * v[dt][j];
            }
            #pragma unroll
            for (int kt = 0; kt < 4; ++kt)
                #pragma unroll
                for (int dt = 0; dt < 2; ++dt)
                    acc[kt][dt] = __builtin_amdgcn_mfma_f32_16x16x32_bf16(
                        afrag[kt], bfrag[dt], acc[kt][dt], 0, 0, 0);
        }
    }

    // ---- epilogue: repack G through LDS (gt distinct from Ft), store coalesced ----
    #pragma unroll
    for (int kt = 0; kt < 4; ++kt)
        #pragma unroll
        for (int dt = 0; dt < 2; ++dt)
            #pragma unroll
            for (int r = 0; r < 4; ++r) {
                const int k = kt * 16 + q * 4 + r;      // C/D row = (lane>>4)*4 + reg
                const int d = wave * 32 + dt * 16 + m;  // C/D col = lane&15
                __half hv = __float2half(acc[kt][dt][r]);
                gt[k * D_DIM + d] = *(unsigned short*)&hv;
            }

    #pragma unroll
    for (int off = 32; off > 0; off >>= 1) trw += __shfl_down(trw, off, 64);
    if (lane == 0) red[wave] = trw;
    __syncthreads();                              // gt complete + red complete

    unsigned short* gp = gpart + (size_t)b * GSZ;
    #pragma unroll
    for (int it = 0; it < 4; ++it)                // 32768 u16 / 1024 thr = 4x 16B
        *(uint4*)(gp + it * 8192 + tid * 8) = *(const uint4*)(gt + it * 8192 + tid * 8);

    if (tid == 0) {
        float s = 0.f;
        #pragma unroll
        for (int w = 0; w < 16; ++w) s += red[w];
        trw_out[b] = s;
    }
}

// K2: out = sum_b trw[b] - sum_{k,d} (sum_b Gpart[b][k,d])^2   (unchanged, proven)
extern "C" __global__ void __launch_bounds__(512)
k2_reduce(const float* __restrict__ trw, const unsigned short* __restrict__ gpart,
          float* __restrict__ out, int P) {
    __shared__ float sh[32 * 16 * 8];   // 16 KB: [sub][oct][j]
    __shared__ float red2[8];

    const int tid = threadIdx.x;
    const int sub = tid >> 4;                  // 0..31 : b-split
    const int oct = tid & 15;
    const int tt  = blockIdx.x * 16 + oct;     // 0..4095 ; elements 8tt..8tt+7

    float g[8];
    #pragma unroll
    for (int j = 0; j < 8; ++j) g[j] = 0.f;

    const unsigned short* base = gpart + (size_t)tt * 8;
    for (int b = sub; b < P; b += 32) {
        half8 v = *(const half8*)(base + (size_t)b * GSZ);
        #pragma unroll
        for (int j = 0; j < 8; ++j) g[j] += (float)v[j];
    }
    #pragma unroll
    for (int j = 0; j < 8; ++j) sh[(sub * 16 + oct) * 8 + j] = g[j];
    __syncthreads();

    float val = 0.f;
    if (tid < 128) {
        const int o2 = tid >> 3, j = tid & 7;
        float s = 0.f;
        #pragma unroll
        for (int sb = 0; sb < 32; ++sb) s += sh[(sb * 16 + o2) * 8 + j];
        val = -s * s;
    } else if (blockIdx.x == 0 && tid - 128 < P) {
        val = trw[tid - 128];                  // fold tr_wtw partials in block 0
    }

    #pragma unroll
    for (int off = 32; off > 0; off >>= 1) val += __shfl_down(val, off, 64);
    if ((tid & 63) == 0) red2[tid >> 6] = val;
    __syncthreads();
    if (tid == 0) {
        float s = 0.f;
        #pragma unroll
        for (int w = 0; w < 8; ++w) s += red2[w];
        atomicAdd(out, s);
    }
}

extern "C" void kernel_launch(void* const* d_in, const int* in_sizes, int n_in,
                              void* d_out, int out_size, void* d_ws, size_t ws_size,
                              hipStream_t stream) {
    const float* h = (const float*)d_in[0];   // [65536, 512]
    const float* F = (const float*)d_in[1];   // [65536, 64]
    float* out = (float*)d_out;

    // ws layout: [0,4096): trw fp32 (P<=256) ; [4096, 4096+P*64KiB): fp16 partial G
    int P = 256;
    while (P > 1 && (size_t)4096 + (size_t)P * (GSZ * 2) > ws_size) P >>= 1;
    const int rowsPerBlock = N_TOT / P;       // multiple of 256 for any P<=256

    float* trw = (float*)d_ws;
    unsigned short* gpart = (unsigned short*)((char*)d_ws + 4096);

    hipLaunchKernelGGL(k1_partial, dim3(P), dim3(1024), 0, stream,
                       h, F, trw, gpart, out, rowsPerBlock);
    hipLaunchKernelGGL(k2_reduce, dim3(256), dim3(512), 0, stream,
                       trw, gpart, out, P);
}